// Round 1
// baseline (681.401 us; speedup 1.0000x reference)
//
#include <hip/hip_runtime.h>
#include <math.h>

// Problem geometry (fixed by the reference: shape (1,1,96,128,128), f32)
#define DX 96
#define DY 128
#define DZ 128
#define NVOX (DX * DY * DZ)   // 1,572,864
#define STRIDE_Y DZ           // 128
#define STRIDE_X (DY * DZ)    // 16384

// Number of fixed-point sweeps m <- sigmoid(E(m)).
// Contraction factor <= 0.75 per sweep => residual <= 0.75^64 ~ 1e-8.
#define NSWEEPS 64

__device__ __forceinline__ float sigmoid_f(float x) {
    return 1.0f / (1.0f + __expf(-x));
}

// e[i] = d[i] + sum over 6 neighbors of r_edge * (2*m[neighbor] - 1)
__device__ __forceinline__ float energy_at(int i, int x, int y, int z,
                                           const float* __restrict__ d,
                                           const float* __restrict__ rx,
                                           const float* __restrict__ ry,
                                           const float* __restrict__ rz,
                                           const float* __restrict__ m) {
    float e = d[i];
    // z-direction (contiguous)
    if (z < DZ - 1) e += rz[i]            * (2.0f * m[i + 1]        - 1.0f);
    if (z > 0)      e += rz[i - 1]        * (2.0f * m[i - 1]        - 1.0f);
    // y-direction
    if (y < DY - 1) e += ry[i]            * (2.0f * m[i + STRIDE_Y] - 1.0f);
    if (y > 0)      e += ry[i - STRIDE_Y] * (2.0f * m[i - STRIDE_Y] - 1.0f);
    // x-direction
    if (x < DX - 1) e += rx[i]            * (2.0f * m[i + STRIDE_X] - 1.0f);
    if (x > 0)      e += rx[i - STRIDE_X] * (2.0f * m[i - STRIDE_X] - 1.0f);
    return e;
}

__global__ void init_m_kernel(const float* __restrict__ d,
                              float* __restrict__ m) {
    int i = blockIdx.x * blockDim.x + threadIdx.x;
    if (i < NVOX) m[i] = sigmoid_f(d[i]);
}

__global__ void sweep_kernel(const float* __restrict__ d,
                             const float* __restrict__ rx,
                             const float* __restrict__ ry,
                             const float* __restrict__ rz,
                             const float* __restrict__ m_in,
                             float* __restrict__ m_out) {
    int i = blockIdx.x * blockDim.x + threadIdx.x;
    if (i >= NVOX) return;
    int z = i & (DZ - 1);
    int y = (i >> 7) & (DY - 1);
    int x = i >> 14;
    float e = energy_at(i, x, y, z, d, rx, ry, rz, m_in);
    m_out[i] = sigmoid_f(e);
}

__global__ void final_energy_kernel(const float* __restrict__ d,
                                    const float* __restrict__ rx,
                                    const float* __restrict__ ry,
                                    const float* __restrict__ rz,
                                    const float* __restrict__ m,
                                    float* __restrict__ out) {
    int i = blockIdx.x * blockDim.x + threadIdx.x;
    if (i >= NVOX) return;
    int z = i & (DZ - 1);
    int y = (i >> 7) & (DY - 1);
    int x = i >> 14;
    out[i] = energy_at(i, x, y, z, d, rx, ry, rz, m);
}

extern "C" void kernel_launch(void* const* d_in, const int* in_sizes, int n_in,
                              void* d_out, int out_size, void* d_ws, size_t ws_size,
                              hipStream_t stream) {
    const float* d  = (const float*)d_in[0];
    const float* rx = (const float*)d_in[1];
    const float* ry = (const float*)d_in[2];
    const float* rz = (const float*)d_in[3];
    float* out = (float*)d_out;

    // Two ping-pong m buffers in workspace (2 * 6.29 MB)
    float* m0 = (float*)d_ws;
    float* m1 = m0 + NVOX;

    const int threads = 256;
    const int blocks = (NVOX + threads - 1) / threads;

    init_m_kernel<<<blocks, threads, 0, stream>>>(d, m0);

    for (int it = 0; it < NSWEEPS; ++it) {
        sweep_kernel<<<blocks, threads, 0, stream>>>(d, rx, ry, rz, m0, m1);
        float* t = m0; m0 = m1; m1 = t;
    }

    final_energy_kernel<<<blocks, threads, 0, stream>>>(d, rx, ry, rz, m0, out);
}

// Round 2
// 189.927 us; speedup vs baseline: 3.5877x; 3.5877x over previous
//
#include <hip/hip_runtime.h>
#include <math.h>

// Problem geometry (fixed by the reference: shape (1,1,96,128,128), f32)
#define DX 96
#define DY 128
#define DZ 128
#define NVOX (DX * DY * DZ)   // 1,572,864
#define NQUAD (NVOX / 4)      // 393,216 float4s
#define STRIDE_Y DZ           // 128
#define STRIDE_X (DY * DZ)    // 16384

// Fixed-point sweeps m <- sigmoid(E(m)). Contraction <= 0.75/sweep:
// residual in m <= 0.75^24 ~ 1.0e-3, energy error <= 3e-3 (threshold 9.75e-2).
#define NSWEEPS 24

__device__ __forceinline__ float sigmoid_f(float x) {
    return 1.0f / (1.0f + __expf(-x));
}

__device__ __forceinline__ float4 ld4(const float* __restrict__ p) {
    return *reinterpret_cast<const float4*>(p);
}

// Computes E at 4 contiguous-z voxels starting at scalar index i = 4*t.
// WRITE_SIGMOID: 1 -> out = sigmoid(E) (sweep), 0 -> out = E (final energy).
template <int WRITE_SIGMOID>
__global__ void sweep4_kernel(const float* __restrict__ d,
                              const float* __restrict__ rx,
                              const float* __restrict__ ry,
                              const float* __restrict__ rz,
                              const float* __restrict__ m_in,
                              float* __restrict__ out) {
    int t = blockIdx.x * blockDim.x + threadIdx.x;
    if (t >= NQUAD) return;
    int zq = t & 31;            // which float4 within the z-row (z = 4*zq)
    int y  = (t >> 5) & 127;
    int x  = t >> 12;
    int i  = t << 2;            // base scalar index (16B aligned)

    float4 e   = ld4(d + i);
    float4 mc  = ld4(m_in + i);
    float4 rzv = ld4(rz + i);

    // z+ neighbors (j=0..2 in-register; j=3 guarded at z=127)
    float mzp = 0.f, rz3 = 0.f;
    if (zq < 31) { mzp = m_in[i + 4]; rz3 = rzv.w; }
    e.x += rzv.x * (2.f * mc.y - 1.f);
    e.y += rzv.y * (2.f * mc.z - 1.f);
    e.z += rzv.z * (2.f * mc.w - 1.f);
    e.w += rz3   * (2.f * mzp  - 1.f);

    // z- neighbors (j=1..3 in-register; j=0 guarded at z=0)
    float mzm = 0.f, rzm = 0.f;
    if (zq > 0) { mzm = m_in[i - 1]; rzm = rz[i - 1]; }
    e.x += rzm   * (2.f * mzm  - 1.f);
    e.y += rzv.x * (2.f * mc.x - 1.f);
    e.z += rzv.y * (2.f * mc.y - 1.f);
    e.w += rzv.z * (2.f * mc.z - 1.f);

    // y+ / y-
    if (y < DY - 1) {
        float4 ryv = ld4(ry + i);
        float4 myp = ld4(m_in + i + STRIDE_Y);
        e.x += ryv.x * (2.f * myp.x - 1.f);
        e.y += ryv.y * (2.f * myp.y - 1.f);
        e.z += ryv.z * (2.f * myp.z - 1.f);
        e.w += ryv.w * (2.f * myp.w - 1.f);
    }
    if (y > 0) {
        float4 rym = ld4(ry + i - STRIDE_Y);
        float4 mym = ld4(m_in + i - STRIDE_Y);
        e.x += rym.x * (2.f * mym.x - 1.f);
        e.y += rym.y * (2.f * mym.y - 1.f);
        e.z += rym.z * (2.f * mym.z - 1.f);
        e.w += rym.w * (2.f * mym.w - 1.f);
    }

    // x+ / x-
    if (x < DX - 1) {
        float4 rxv = ld4(rx + i);
        float4 mxp = ld4(m_in + i + STRIDE_X);
        e.x += rxv.x * (2.f * mxp.x - 1.f);
        e.y += rxv.y * (2.f * mxp.y - 1.f);
        e.z += rxv.z * (2.f * mxp.z - 1.f);
        e.w += rxv.w * (2.f * mxp.w - 1.f);
    }
    if (x > 0) {
        float4 rxm = ld4(rx + i - STRIDE_X);
        float4 mxm = ld4(m_in + i - STRIDE_X);
        e.x += rxm.x * (2.f * mxm.x - 1.f);
        e.y += rxm.y * (2.f * mxm.y - 1.f);
        e.z += rxm.z * (2.f * mxm.z - 1.f);
        e.w += rxm.w * (2.f * mxm.w - 1.f);
    }

    float4 o;
    if (WRITE_SIGMOID) {
        o.x = sigmoid_f(e.x); o.y = sigmoid_f(e.y);
        o.z = sigmoid_f(e.z); o.w = sigmoid_f(e.w);
    } else {
        o = e;
    }
    *reinterpret_cast<float4*>(out + i) = o;
}

__global__ void init_m4_kernel(const float* __restrict__ d,
                               float* __restrict__ m) {
    int t = blockIdx.x * blockDim.x + threadIdx.x;
    if (t >= NQUAD) return;
    int i = t << 2;
    float4 dv = ld4(d + i);
    float4 o;
    o.x = sigmoid_f(dv.x); o.y = sigmoid_f(dv.y);
    o.z = sigmoid_f(dv.z); o.w = sigmoid_f(dv.w);
    *reinterpret_cast<float4*>(m + i) = o;
}

extern "C" void kernel_launch(void* const* d_in, const int* in_sizes, int n_in,
                              void* d_out, int out_size, void* d_ws, size_t ws_size,
                              hipStream_t stream) {
    const float* d  = (const float*)d_in[0];
    const float* rx = (const float*)d_in[1];
    const float* ry = (const float*)d_in[2];
    const float* rz = (const float*)d_in[3];
    float* out = (float*)d_out;

    // Two ping-pong m buffers in workspace (2 * 6.29 MB)
    float* m0 = (float*)d_ws;
    float* m1 = m0 + NVOX;

    const int threads = 256;
    const int blocks = (NQUAD + threads - 1) / threads;  // 1536

    init_m4_kernel<<<blocks, threads, 0, stream>>>(d, m0);

    for (int it = 0; it < NSWEEPS; ++it) {
        sweep4_kernel<1><<<blocks, threads, 0, stream>>>(d, rx, ry, rz, m0, m1);
        float* t = m0; m0 = m1; m1 = t;
    }

    sweep4_kernel<0><<<blocks, threads, 0, stream>>>(d, rx, ry, rz, m0, out);
}